// Round 5
// baseline (321.451 us; speedup 1.0000x reference)
//
#include <hip/hip_runtime.h>
#include <math.h>

#define D_MODEL 2048
#define KB_ 64
#define NCHUNK 32

typedef __bf16 bf16;
typedef __attribute__((ext_vector_type(8))) __bf16 bf16x8;
typedef __attribute__((ext_vector_type(4))) __bf16 bf16x4;
typedef __attribute__((ext_vector_type(4))) float f32x4;

// ---- workspace layout (float offsets) ----
#define OFF_COEFFS 0                           // [32][64][2048]
#define OFF_NSQ    (32 * 64 * 2048)            // [32][64][32] per-dtile sumsq partials
#define OFF_NORMS  (OFF_NSQ + 32 * 64 * 32)    // [32][64] final norms
#define OFF_PARTR  (OFF_NORMS + 2048)          // [32][2048]
#define OFF_PARTI  (OFF_PARTR + 32 * 2048)     // [32][2048]
#define OFF_CTX    (OFF_PARTI + 32 * 2048)     // [2048]
#define OFF_CHEB2  (OFF_CTX + 2048)            // 32768 bf16 = 16384 floats

// ---------------------------------------------------------------------------
// K0: cheb2 = bf16(cheby), same [64][512] layout
// ---------------------------------------------------------------------------
__global__ __launch_bounds__(256) void k0_prep(
    const float* __restrict__ cheby, bf16* __restrict__ cheb2)
{
  int flat = blockIdx.x * 256 + threadIdx.x;   // 0..32767
  cheb2[flat] = (bf16)cheby[flat];
}

// ---------------------------------------------------------------------------
// K1: window form, double-buffered LDS, register prefetch.
// Block (dt, c): coeffs[c][band][d0..d0+64) = scale * sum_n cheby[band][n]*win[n][d]
// win_c = [chunk_{c-1} (buf[256:512] if c==0); chunk_c]
// 4 waves; wave w: bands [w*16,(w+1)*16) x 64 d. One barrier per 64-n slice.
// Also writes nsq_part[c][band][dt].
// ---------------------------------------------------------------------------
__global__ __launch_bounds__(256, 4) void k1_mfma(
    const float* __restrict__ scan, const float* __restrict__ buf,
    const bf16* __restrict__ cheb2, float* __restrict__ coeffs,
    float* __restrict__ nsq_part)
{
  __shared__ bf16 Bs[2][64 * 72];   // [buf][d][72]: 64 n-slots + pad

  const int t = threadIdx.x;
  const int dt = blockIdx.x;     // 0..31 d-tile
  const int c  = blockIdx.y;     // 0..31 window
  const int w = t >> 6, lane = t & 63;
  const int quad = lane >> 4, r16 = lane & 15;
  const int d0 = dt * 64;
  const int n0 = (t >> 4) * 4;   // staging: 4 n-rows per thread
  const int d4 = (t & 15) * 4;   // staging: 4 d-cols per thread
  const float* scan1 = scan + 8192 * 2048;

  f32x4 acc[4];
#pragma unroll
  for (int tn = 0; tn < 4; ++tn) acc[tn] = (f32x4){0.f, 0.f, 0.f, 0.f};

  float vv[4][4], vvn[4][4];

  auto loadB = [&](int nb, float (*v)[4]) {
    if (c == 0 && nb < 4) {
      const float* bp = buf + (256 + nb * 64 + n0) * 2048 + d0 + d4;
#pragma unroll
      for (int i = 0; i < 4; ++i) {
        float4 x = *(const float4*)(bp + i * 2048);
        v[i][0] = x.x; v[i][1] = x.y; v[i][2] = x.z; v[i][3] = x.w;
      }
    } else {
      int gbase = ((c - 1) * 256 + nb * 64 + n0) * 2048 + d0 + d4;
#pragma unroll
      for (int i = 0; i < 4; ++i) {
        float4 a = *(const float4*)(scan + gbase + i * 2048);
        float4 b = *(const float4*)(scan1 + gbase + i * 2048);
        v[i][0] = 0.5f * (a.x + b.x); v[i][1] = 0.5f * (a.y + b.y);
        v[i][2] = 0.5f * (a.z + b.z); v[i][3] = 0.5f * (a.w + b.w);
      }
    }
  };

  loadB(0, vv);
  for (int nb = 0; nb < 8; ++nb) {
    bf16* Bw = Bs[nb & 1];
#pragma unroll
    for (int x = 0; x < 4; ++x) {
      bf16x4 e = {(bf16)vv[0][x], (bf16)vv[1][x], (bf16)vv[2][x], (bf16)vv[3][x]};
      *(bf16x4*)(Bw + (d4 + x) * 72 + n0) = e;
    }
    __syncthreads();
    if (nb < 7) loadB(nb + 1, vvn);   // prefetch: global loads in flight over MFMA
    const bf16* abase = cheb2 + (w * 16 + r16) * 512 + nb * 64 + quad * 8;
    bf16x8 a0 = *(const bf16x8*)(abase);
    bf16x8 a1 = *(const bf16x8*)(abase + 32);
#pragma unroll
    for (int ks = 0; ks < 2; ++ks) {
      bf16x8 a = ks ? a1 : a0;
#pragma unroll
      for (int tn = 0; tn < 4; ++tn) {
        bf16x8 bfr = *(const bf16x8*)(Bw + (tn * 16 + r16) * 72 + ks * 32 + quad * 8);
        acc[tn] = __builtin_amdgcn_mfma_f32_16x16x32_bf16(a, bfr, acc[tn], 0, 0, 0);
      }
    }
#pragma unroll
    for (int i = 0; i < 4; ++i)
#pragma unroll
      for (int x = 0; x < 4; ++x) vv[i][x] = vvn[i][x];
  }

  // epilogue: scale, store, per-band sumsq partial
  const float scale = 2.0f / 512.0f;
  float sq[4] = {0.f, 0.f, 0.f, 0.f};
#pragma unroll
  for (int tn = 0; tn < 4; ++tn) {
#pragma unroll
    for (int rr = 0; rr < 4; ++rr) {
      int band = w * 16 + quad * 4 + rr;
      float sc = (band == 0) ? scale * 0.5f : scale;
      float v = acc[tn][rr] * sc;
      coeffs[(c * 64 + band) * 2048 + d0 + tn * 16 + r16] = v;
      sq[rr] += v * v;
    }
  }
#pragma unroll
  for (int off = 8; off > 0; off >>= 1) {
#pragma unroll
    for (int rr = 0; rr < 4; ++rr) sq[rr] += __shfl_down(sq[rr], off);
  }
  if (r16 == 0) {
#pragma unroll
    for (int rr = 0; rr < 4; ++rr)
      nsq_part[(c * 64 + w * 16 + quad * 4 + rr) * 32 + dt] = sq[rr];
  }
}

// ---------------------------------------------------------------------------
// K3: grid (3, 32).
//  x<2: finalize norms (from nsq_part) + partial binds per (c, d-half)
//  x==2: delta for k = c and c+32 -> dout[2048+k]
// ---------------------------------------------------------------------------
__global__ __launch_bounds__(256) void k3_bind(
    const float* __restrict__ coeffs, const float* __restrict__ nsq_part,
    const float* __restrict__ rr, const float* __restrict__ ri,
    float* __restrict__ part_r, float* __restrict__ part_i,
    float* __restrict__ norms, float* __restrict__ dout)
{
  const int tid = threadIdx.x;
  const int c = blockIdx.y;

  if (blockIdx.x == 2) {
    // delta blocks: two k's per block
    __shared__ float red[4];
#pragma unroll
    for (int kk = 0; kk < 2; ++kk) {
      int k = c + kk * 32;
      const float* p1 = coeffs + (31 * 64 + k) * 2048;
      const float* p0 = coeffs + (30 * 64 + k) * 2048;
      float s = 0.f;
#pragma unroll
      for (int i = 0; i < 2; ++i) {
        float4 a = *(const float4*)(p1 + tid * 4 + i * 1024);
        float4 b = *(const float4*)(p0 + tid * 4 + i * 1024);
        float x = a.x - b.x, y = a.y - b.y, z = a.z - b.z, ww = a.w - b.w;
        s += x * x + y * y + z * z + ww * ww;
      }
      for (int o = 32; o > 0; o >>= 1) s += __shfl_down(s, o, 64);
      if ((tid & 63) == 0) red[tid >> 6] = s;
      __syncthreads();
      if (tid == 0) dout[D_MODEL + k] = sqrtf(red[0] + red[1] + red[2] + red[3]);
      __syncthreads();
    }
    return;
  }

  __shared__ float inv_s[64];
  if (tid < 64) {
    float s = 0.f;
#pragma unroll
    for (int dtl = 0; dtl < 32; ++dtl) s += nsq_part[(c * 64 + tid) * 32 + dtl];
    float nrm = fmaxf(sqrtf(s), 1e-12f);
    inv_s[tid] = 1.0f / nrm;
    if (blockIdx.x == 0) norms[c * 64 + tid] = nrm;
  }
  __syncthreads();
  const int d4 = (blockIdx.x * 256 + tid) * 4;
  const float wc = 0.1f * powf(0.9f, (float)(31 - c));
  float4 ar = make_float4(0.f, 0.f, 0.f, 0.f);
  float4 ai = make_float4(0.f, 0.f, 0.f, 0.f);
  for (int k = 0; k < KB_; ++k) {
    float4 cf = *(const float4*)(coeffs + (c * 64 + k) * 2048 + d4);
    float inv = inv_s[k];
    float4 r = *(const float4*)(rr + k * D_MODEL + d4);
    float4 im = *(const float4*)(ri + k * D_MODEL + d4);
    float cx = cf.x * inv, cy = cf.y * inv, cz = cf.z * inv, cw = cf.w * inv;
    ar.x += cx * r.x; ar.y += cy * r.y; ar.z += cz * r.z; ar.w += cw * r.w;
    ai.x += cx * im.x; ai.y += cy * im.y; ai.z += cz * im.z; ai.w += cw * im.w;
  }
  *(float4*)(part_r + c * D_MODEL + d4) =
      make_float4(wc * ar.x, wc * ar.y, wc * ar.z, wc * ar.w);
  *(float4*)(part_i + c * D_MODEL + d4) =
      make_float4(wc * ai.x, wc * ai.y, wc * ai.z, wc * ai.w);
}

// ---------------------------------------------------------------------------
// K4: cnorms EMA + top-8 (redundant per block, cheap), vr/vi -> d_out, ctx
// ---------------------------------------------------------------------------
__global__ __launch_bounds__(256) void k4_ctx(
    const float* __restrict__ norms, const float* __restrict__ part_r,
    const float* __restrict__ part_i, const float* __restrict__ rr,
    const float* __restrict__ ri, const float* __restrict__ wbands,
    float* __restrict__ dout, float* __restrict__ ctx)
{
  __shared__ float cn_s[64];
  __shared__ int top_s[8];
  __shared__ float wgt_s[8];
  const int tid = threadIdx.x;
  const int d = blockIdx.x * 256 + tid;
  if (tid < 64) {
    float s = 0.f;
    for (int c = 0; c < NCHUNK; ++c) s = 0.9f * s + 0.1f * norms[c * 64 + tid];
    cn_s[tid] = fmaxf(s, 1e-12f);
  }
  __syncthreads();
  if (tid == 0) {
    unsigned long long taken = 0ULL;
    for (int jj = 0; jj < 8; ++jj) {
      float best = -1.f;
      int bi = 0;
      for (int k = 0; k < 64; ++k) {
        float dv = dout[D_MODEL + k];
        if (!((taken >> k) & 1ULL) && dv > best) { best = dv; bi = k; }
      }
      taken |= (1ULL << bi);
      top_s[jj] = bi;
      wgt_s[jj] = log1pf(expf(wbands[bi]));  // softplus
    }
  }
  __syncthreads();
  float sr = 0.f, si = 0.f;
  for (int c = 0; c < NCHUNK; ++c) {
    sr += part_r[c * D_MODEL + d];
    si += part_i[c * D_MODEL + d];
  }
  dout[D_MODEL + KB_ + d] = sr;
  dout[D_MODEL + KB_ + D_MODEL + d] = si;
  float cx = 0.f;
#pragma unroll
  for (int jj = 0; jj < 8; ++jj) {
    int k = top_s[jj];
    cx += wgt_s[jj] * (sr * rr[k * D_MODEL + d] + si * ri[k * D_MODEL + d]) * cn_s[k];
  }
  ctx[d] = cx;
}

// K5b: out[d] = sigmoid(gate) * sum_e ctx[e]*Wp[d][e]; one wave per row
__global__ __launch_bounds__(256) void k5b_gemv(
    const float* __restrict__ Wp, const float* __restrict__ ctx,
    const float* __restrict__ gate, float* __restrict__ dout)
{
  const int tid = threadIdx.x;
  const int lane = tid & 63;
  const int w = tid >> 6;
  const int row = blockIdx.x * 4 + w;
  const float* p = Wp + row * D_MODEL;
  float s = 0.f;
#pragma unroll
  for (int i = 0; i < 8; ++i) {
    int e = lane * 4 + i * 256;
    float4 wv = *(const float4*)(p + e);
    float4 cv = *(const float4*)(ctx + e);
    s += wv.x * cv.x + wv.y * cv.y + wv.z * cv.z + wv.w * cv.w;
  }
  for (int o = 32; o > 0; o >>= 1) s += __shfl_down(s, o, 64);
  if (lane == 0) {
    float sig = 1.f / (1.f + expf(-gate[0]));
    dout[row] = s * sig;
  }
}

extern "C" void kernel_launch(void* const* d_in, const int* in_sizes, int n_in,
                              void* d_out, int out_size, void* d_ws, size_t ws_size,
                              hipStream_t stream) {
  const float* scan  = (const float*)d_in[0];
  const float* buf   = (const float*)d_in[1];
  const float* rr    = (const float*)d_in[2];
  const float* ri    = (const float*)d_in[3];
  const float* wb    = (const float*)d_in[4];
  const float* Wp    = (const float*)d_in[5];
  const float* gate  = (const float*)d_in[6];
  const float* cheby = (const float*)d_in[7];
  float* out = (float*)d_out;
  float* ws = (float*)d_ws;

  float* coeffs   = ws + OFF_COEFFS;
  float* nsq_part = ws + OFF_NSQ;
  float* norms    = ws + OFF_NORMS;
  float* part_r   = ws + OFF_PARTR;
  float* part_i   = ws + OFF_PARTI;
  float* ctx      = ws + OFF_CTX;
  bf16*  cheb2    = (bf16*)(ws + OFF_CHEB2);

  k0_prep<<<128, 256, 0, stream>>>(cheby, cheb2);
  k1_mfma<<<dim3(32, 32), 256, 0, stream>>>(scan, buf, cheb2, coeffs, nsq_part);
  k3_bind<<<dim3(3, NCHUNK), 256, 0, stream>>>(coeffs, nsq_part, rr, ri,
                                               part_r, part_i, norms, out);
  k4_ctx<<<8, 256, 0, stream>>>(norms, part_r, part_i, rr, ri, wb, out, ctx);
  k5b_gemv<<<512, 256, 0, stream>>>(Wp, ctx, gate, out);
}

// Round 6
// 294.732 us; speedup vs baseline: 1.0907x; 1.0907x over previous
//
#include <hip/hip_runtime.h>
#include <math.h>

#define D_MODEL 2048
#define KB_ 64
#define NCHUNK 32

typedef __bf16 bf16;
typedef __attribute__((ext_vector_type(8))) __bf16 bf16x8;
typedef __attribute__((ext_vector_type(4))) __bf16 bf16x4;
typedef __attribute__((ext_vector_type(4))) float f32x4;

// ---- workspace layout (float offsets) ----
#define HALF_SZ   (32 * 64 * 2048)
#define OFF_CA    0                       // coeffs half A (n 0..255)
#define OFF_CB    HALF_SZ                 // coeffs half B (n 256..511)
#define OFF_NORMS (2 * HALF_SZ)           // [32][64]
#define OFF_PARTR (OFF_NORMS + 2048)      // [32][2048]
#define OFF_PARTI (OFF_PARTR + 32 * 2048) // [32][2048]
#define OFF_CTX   (OFF_PARTI + 32 * 2048) // [2048]
#define OFF_CHEB2 (OFF_CTX + 2048)        // 32768 bf16 = 16384 floats

// ---------------------------------------------------------------------------
// K0: cheb2 = bf16(cheby), same [64][512] layout
// ---------------------------------------------------------------------------
__global__ __launch_bounds__(256) void k0_prep(
    const float* __restrict__ cheby, bf16* __restrict__ cheb2)
{
  int flat = blockIdx.x * 256 + threadIdx.x;   // 0..32767
  cheb2[flat] = (bf16)cheby[flat];
}

// ---------------------------------------------------------------------------
// K1: half-window form. Block (dt, c, h): for n-slice range s = h*4 .. h*4+3,
//   coeff_half[h][c][band][d0+d] = scale * sum_{n in half} cheby[band][n]*win[n][d]
// win_c = [chunk_{c-1} (buf[256:512] if c==0); chunk_c]
// 4 waves; wave w: bands [w*16,(w+1)*16) x 64 d; simple 2-barrier loop (R4 form).
// ---------------------------------------------------------------------------
__global__ __launch_bounds__(256, 6) void k1_mfma(
    const float* __restrict__ scan, const float* __restrict__ buf,
    const bf16* __restrict__ cheb2, float* __restrict__ coeffsA,
    float* __restrict__ coeffsB)
{
  __shared__ bf16 Bs[64 * 72];   // [d][72]: 64 n-slots + pad

  const int t = threadIdx.x;
  const int dt = blockIdx.x;     // 0..31 d-tile
  const int c  = blockIdx.y;     // 0..31 window
  const int h  = blockIdx.z;     // 0..1 half
  const int w = t >> 6, lane = t & 63;
  const int quad = lane >> 4, r16 = lane & 15;
  const int d0 = dt * 64;
  const int n0 = (t >> 4) * 4;   // staging: 4 n-rows per thread
  const int d4 = (t & 15) * 4;   // staging: 4 d-cols per thread
  const float* scan1 = scan + 8192 * 2048;

  f32x4 acc[4];
#pragma unroll
  for (int tn = 0; tn < 4; ++tn) acc[tn] = (f32x4){0.f, 0.f, 0.f, 0.f};

  for (int nb = 0; nb < 4; ++nb) {
    const int s = h * 4 + nb;    // global 64-n slice index 0..7
    // B staging: rows (s*64+n0 ..+3), cols d4..d4+3 of the window
    float vv[4][4];
    if (c == 0 && h == 0) {
      const float* bp = buf + (256 + s * 64 + n0) * 2048 + d0 + d4;
#pragma unroll
      for (int i = 0; i < 4; ++i) {
        float4 x = *(const float4*)(bp + i * 2048);
        vv[i][0] = x.x; vv[i][1] = x.y; vv[i][2] = x.z; vv[i][3] = x.w;
      }
    } else {
      int gbase = ((c - 1 + h) * 256 + nb * 64 + n0) * 2048 + d0 + d4;
#pragma unroll
      for (int i = 0; i < 4; ++i) {
        float4 a = *(const float4*)(scan + gbase + i * 2048);
        float4 b = *(const float4*)(scan1 + gbase + i * 2048);
        vv[i][0] = 0.5f * (a.x + b.x); vv[i][1] = 0.5f * (a.y + b.y);
        vv[i][2] = 0.5f * (a.z + b.z); vv[i][3] = 0.5f * (a.w + b.w);
      }
    }
    __syncthreads();   // prior iteration's reads done before overwrite
#pragma unroll
    for (int x = 0; x < 4; ++x) {
      bf16x4 e = {(bf16)vv[0][x], (bf16)vv[1][x], (bf16)vv[2][x], (bf16)vv[3][x]};
      *(bf16x4*)(Bs + (d4 + x) * 72 + n0) = e;
    }
    __syncthreads();

    const bf16* abase = cheb2 + (w * 16 + r16) * 512 + s * 64 + quad * 8;
    bf16x8 a0 = *(const bf16x8*)(abase);
    bf16x8 a1 = *(const bf16x8*)(abase + 32);
#pragma unroll
    for (int ks = 0; ks < 2; ++ks) {
      bf16x8 a = ks ? a1 : a0;
#pragma unroll
      for (int tn = 0; tn < 4; ++tn) {
        bf16x8 bfr = *(const bf16x8*)(Bs + (tn * 16 + r16) * 72 + ks * 32 + quad * 8);
        acc[tn] = __builtin_amdgcn_mfma_f32_16x16x32_bf16(a, bfr, acc[tn], 0, 0, 0);
      }
    }
  }

  // epilogue: scale + store this half's partial coefficients
  const float scale = 2.0f / 512.0f;
  float* dst = h ? coeffsB : coeffsA;
#pragma unroll
  for (int tn = 0; tn < 4; ++tn) {
#pragma unroll
    for (int rr = 0; rr < 4; ++rr) {
      int band = w * 16 + quad * 4 + rr;
      float sc = (band == 0) ? scale * 0.5f : scale;
      dst[(c * 64 + band) * 2048 + d0 + tn * 16 + r16] = acc[tn][rr] * sc;
    }
  }
}

// ---------------------------------------------------------------------------
// K2: blocks 0..2047: norms[c][k] = max(||A[c][k]+B[c][k]||, eps)
//     blocks 2048..2111: delta[k] -> dout[2048+k]
// ---------------------------------------------------------------------------
__global__ __launch_bounds__(256) void k2_norms(
    const float* __restrict__ CA, const float* __restrict__ CB,
    float* __restrict__ norms, float* __restrict__ dout)
{
  const int tid = threadIdx.x;
  const int b = blockIdx.x;
  float s = 0.f;
  if (b < NCHUNK * KB_) {
    const float* pa = CA + b * 2048;
    const float* pb = CB + b * 2048;
#pragma unroll
    for (int i = 0; i < 2; ++i) {
      float4 a = *(const float4*)(pa + tid * 4 + i * 1024);
      float4 bb = *(const float4*)(pb + tid * 4 + i * 1024);
      float x = a.x + bb.x, y = a.y + bb.y, z = a.z + bb.z, ww = a.w + bb.w;
      s += x * x + y * y + z * z + ww * ww;
    }
  } else {
    int k = b - NCHUNK * KB_;
    const float* a1 = CA + (31 * 64 + k) * 2048;
    const float* b1 = CB + (31 * 64 + k) * 2048;
    const float* a0 = CA + (30 * 64 + k) * 2048;
    const float* b0 = CB + (30 * 64 + k) * 2048;
#pragma unroll
    for (int i = 0; i < 2; ++i) {
      float4 va1 = *(const float4*)(a1 + tid * 4 + i * 1024);
      float4 vb1 = *(const float4*)(b1 + tid * 4 + i * 1024);
      float4 va0 = *(const float4*)(a0 + tid * 4 + i * 1024);
      float4 vb0 = *(const float4*)(b0 + tid * 4 + i * 1024);
      float x = va1.x + vb1.x - va0.x - vb0.x, y = va1.y + vb1.y - va0.y - vb0.y;
      float z = va1.z + vb1.z - va0.z - vb0.z, ww = va1.w + vb1.w - va0.w - vb0.w;
      s += x * x + y * y + z * z + ww * ww;
    }
  }
  for (int o = 32; o > 0; o >>= 1) s += __shfl_down(s, o, 64);
  __shared__ float red[4];
  if ((tid & 63) == 0) red[tid >> 6] = s;
  __syncthreads();
  if (tid == 0) {
    float r = sqrtf(red[0] + red[1] + red[2] + red[3]);
    if (b < NCHUNK * KB_) norms[b] = fmaxf(r, 1e-12f);
    else dout[D_MODEL + (b - NCHUNK * KB_)] = r;
  }
}

// ---------------------------------------------------------------------------
// K3: partial binds per (c, d-half): part_r/i[c][d] = wc * sum_k cn*role
// ---------------------------------------------------------------------------
__global__ __launch_bounds__(256) void k3_bind(
    const float* __restrict__ CA, const float* __restrict__ CB,
    const float* __restrict__ norms, const float* __restrict__ rr,
    const float* __restrict__ ri, float* __restrict__ part_r,
    float* __restrict__ part_i)
{
  __shared__ float inv_s[64];
  const int tid = threadIdx.x;
  const int c = blockIdx.y;
  if (tid < 64) inv_s[tid] = 1.0f / norms[c * 64 + tid];
  __syncthreads();
  const int d4 = (blockIdx.x * 256 + tid) * 4;
  const float wc = 0.1f * powf(0.9f, (float)(31 - c));
  float4 ar = make_float4(0.f, 0.f, 0.f, 0.f);
  float4 ai = make_float4(0.f, 0.f, 0.f, 0.f);
  for (int k = 0; k < KB_; ++k) {
    float4 ca = *(const float4*)(CA + (c * 64 + k) * 2048 + d4);
    float4 cb = *(const float4*)(CB + (c * 64 + k) * 2048 + d4);
    float inv = inv_s[k];
    float4 r = *(const float4*)(rr + k * D_MODEL + d4);
    float4 im = *(const float4*)(ri + k * D_MODEL + d4);
    float cx = (ca.x + cb.x) * inv, cy = (ca.y + cb.y) * inv;
    float cz = (ca.z + cb.z) * inv, cw = (ca.w + cb.w) * inv;
    ar.x += cx * r.x; ar.y += cy * r.y; ar.z += cz * r.z; ar.w += cw * r.w;
    ai.x += cx * im.x; ai.y += cy * im.y; ai.z += cz * im.z; ai.w += cw * im.w;
  }
  *(float4*)(part_r + c * D_MODEL + d4) =
      make_float4(wc * ar.x, wc * ar.y, wc * ar.z, wc * ar.w);
  *(float4*)(part_i + c * D_MODEL + d4) =
      make_float4(wc * ai.x, wc * ai.y, wc * ai.z, wc * ai.w);
}

// ---------------------------------------------------------------------------
// K4: cnorms EMA + top-8 (redundant per block, cheap), vr/vi -> d_out, ctx
// ---------------------------------------------------------------------------
__global__ __launch_bounds__(256) void k4_ctx(
    const float* __restrict__ norms, const float* __restrict__ part_r,
    const float* __restrict__ part_i, const float* __restrict__ rr,
    const float* __restrict__ ri, const float* __restrict__ wbands,
    float* __restrict__ dout, float* __restrict__ ctx)
{
  __shared__ float cn_s[64];
  __shared__ int top_s[8];
  __shared__ float wgt_s[8];
  const int tid = threadIdx.x;
  const int d = blockIdx.x * 256 + tid;
  if (tid < 64) {
    float s = 0.f;
    for (int c = 0; c < NCHUNK; ++c) s = 0.9f * s + 0.1f * norms[c * 64 + tid];
    cn_s[tid] = fmaxf(s, 1e-12f);
  }
  __syncthreads();
  if (tid == 0) {
    unsigned long long taken = 0ULL;
    for (int jj = 0; jj < 8; ++jj) {
      float best = -1.f;
      int bi = 0;
      for (int k = 0; k < 64; ++k) {
        float dv = dout[D_MODEL + k];
        if (!((taken >> k) & 1ULL) && dv > best) { best = dv; bi = k; }
      }
      taken |= (1ULL << bi);
      top_s[jj] = bi;
      wgt_s[jj] = log1pf(expf(wbands[bi]));  // softplus
    }
  }
  __syncthreads();
  float sr = 0.f, si = 0.f;
  for (int c = 0; c < NCHUNK; ++c) {
    sr += part_r[c * D_MODEL + d];
    si += part_i[c * D_MODEL + d];
  }
  dout[D_MODEL + KB_ + d] = sr;
  dout[D_MODEL + KB_ + D_MODEL + d] = si;
  float cx = 0.f;
#pragma unroll
  for (int jj = 0; jj < 8; ++jj) {
    int k = top_s[jj];
    cx += wgt_s[jj] * (sr * rr[k * D_MODEL + d] + si * ri[k * D_MODEL + d]) * cn_s[k];
  }
  ctx[d] = cx;
}

// K5b: out[d] = sigmoid(gate) * sum_e ctx[e]*Wp[d][e]; one wave per row
__global__ __launch_bounds__(256) void k5b_gemv(
    const float* __restrict__ Wp, const float* __restrict__ ctx,
    const float* __restrict__ gate, float* __restrict__ dout)
{
  const int tid = threadIdx.x;
  const int lane = tid & 63;
  const int w = tid >> 6;
  const int row = blockIdx.x * 4 + w;
  const float* p = Wp + row * D_MODEL;
  float s = 0.f;
#pragma unroll
  for (int i = 0; i < 8; ++i) {
    int e = lane * 4 + i * 256;
    float4 wv = *(const float4*)(p + e);
    float4 cv = *(const float4*)(ctx + e);
    s += wv.x * cv.x + wv.y * cv.y + wv.z * cv.z + wv.w * cv.w;
  }
  for (int o = 32; o > 0; o >>= 1) s += __shfl_down(s, o, 64);
  if (lane == 0) {
    float sig = 1.f / (1.f + expf(-gate[0]));
    dout[row] = s * sig;
  }
}

extern "C" void kernel_launch(void* const* d_in, const int* in_sizes, int n_in,
                              void* d_out, int out_size, void* d_ws, size_t ws_size,
                              hipStream_t stream) {
  const float* scan  = (const float*)d_in[0];
  const float* buf   = (const float*)d_in[1];
  const float* rr    = (const float*)d_in[2];
  const float* ri    = (const float*)d_in[3];
  const float* wb    = (const float*)d_in[4];
  const float* Wp    = (const float*)d_in[5];
  const float* gate  = (const float*)d_in[6];
  const float* cheby = (const float*)d_in[7];
  float* out = (float*)d_out;
  float* ws = (float*)d_ws;

  float* CA     = ws + OFF_CA;
  float* CB     = ws + OFF_CB;
  float* norms  = ws + OFF_NORMS;
  float* part_r = ws + OFF_PARTR;
  float* part_i = ws + OFF_PARTI;
  float* ctx    = ws + OFF_CTX;
  bf16*  cheb2  = (bf16*)(ws + OFF_CHEB2);

  k0_prep<<<128, 256, 0, stream>>>(cheby, cheb2);
  k1_mfma<<<dim3(32, 32, 2), 256, 0, stream>>>(scan, buf, cheb2, CA, CB);
  k2_norms<<<NCHUNK * KB_ + KB_, 256, 0, stream>>>(CA, CB, norms, out);
  k3_bind<<<dim3(2, NCHUNK), 256, 0, stream>>>(CA, CB, norms, rr, ri,
                                               part_r, part_i);
  k4_ctx<<<8, 256, 0, stream>>>(norms, part_r, part_i, rr, ri, wb, out, ctx);
  k5b_gemv<<<512, 256, 0, stream>>>(Wp, ctx, gate, out);
}